// Round 8
// baseline (200.087 us; speedup 1.0000x reference)
//
#include <hip/hip_runtime.h>
#include <math.h>

// Problem constants
#define Bq 2
#define Nn 20000
#define Ee 20000
#define Aa 8
#define Hh 256
#define TEe 32
#define NTy 16
constexpr int BE   = Bq * Ee;    // 40000
constexpr int BN   = Bq * Nn;    // 40000
constexpr int KTE  = 8;          // edge GEMM K-tiles (256/32)
constexpr int KTU  = 16;         // node GEMM K-tiles (512/32)
constexpr int SCB  = 1024;       // scan block size
constexpr int NSB  = (BN + SCB - 1) / SCB;   // 40

typedef __attribute__((ext_vector_type(8))) short bf16x8;
typedef __attribute__((ext_vector_type(4))) float f32x4;
typedef unsigned short u16;
typedef unsigned int   u32;

__device__ __forceinline__ u16 f2bf(float f) {           // RNE f32 -> bf16
    u32 u = __float_as_uint(f);
    u32 r = u + 0x7FFFu + ((u >> 16) & 1u);
    return (u16)(r >> 16);
}
__device__ __forceinline__ float bf2f(u16 h) {
    return __uint_as_float(((u32)h) << 16);
}
__device__ __forceinline__ float gelu_f(float x) {
    return 0.5f * x * (1.f + erff(x * 0.70710678118654752440f));
}
__device__ __forceinline__ f32x4 mfma16(bf16x8 a, bf16x8 b, f32x4 c) {
    return __builtin_amdgcn_mfma_f32_16x16x32_bf16(a, b, c, 0, 0, 0);
}

// mask dtype sniffing: bit1 => f32 mask, bit0 => u8 mask, none => i32
__device__ __forceinline__ float mask_at(const void* mp, int flag, int i) {
    if (flag & 2) return ((const float*)mp)[i];
    if (flag & 1) return ((const unsigned char*)mp)[i] ? 1.f : 0.f;
    return ((const int*)mp)[i] ? 1.f : 0.f;
}

__global__ void k_zero2(float4* a, int n4a, float4* b, int n4b) {
    int i = blockIdx.x * blockDim.x + threadIdx.x;
    int stride = gridDim.x * blockDim.x;
    float4 z; z.x = 0.f; z.y = 0.f; z.z = 0.f; z.w = 0.f;
    for (int j = i; j < n4a; j += stride) a[j] = z;
    for (int j = i; j < n4b; j += stride) b[j] = z;
}

__global__ void k_detect(const unsigned int* mw, int n, int* flag) {
    int found = 0;
    for (int i = blockIdx.x * blockDim.x + threadIdx.x; i < n;
         i += gridDim.x * blockDim.x) {
        unsigned int w = mw[i];
        if (w == 0x3F800000u) found |= 2;
        else if (w > 1u) found |= 1;
    }
    __shared__ int sf;
    if (threadIdx.x == 0) sf = 0;
    __syncthreads();
    if (found) atomicOr(&sf, found);
    __syncthreads();
    if (threadIdx.x == 0 && sf) atomicOr(flag, sf);
}

__global__ void k_cvt(const float4* __restrict__ in, ushort4* __restrict__ o, int n4) {
    for (int i = blockIdx.x * blockDim.x + threadIdx.x; i < n4;
         i += gridDim.x * blockDim.x) {
        float4 v = in[i];
        ushort4 u; u.x = f2bf(v.x); u.y = f2bf(v.y); u.z = f2bf(v.z); u.w = f2bf(v.w);
        o[i] = u;
    }
}

// pack W [K][256] f32 into MFMA B-fragment order (KT k-tiles of 32)
__global__ void k_pack(const float* __restrict__ W, u16* __restrict__ Wp,
                       int KT, int nthreads) {
    int t = blockIdx.x * blockDim.x + threadIdx.x;
    if (t >= nthreads) return;
    int lane = t & 63, tile = t >> 6;
    int kt = tile % KT, nt = tile / KT;
    int kbase = kt * 32 + (lane >> 4) * 8;
    int col = nt * 16 + (lane & 15);
    u16 tmp[8];
    #pragma unroll
    for (int j = 0; j < 8; j++) tmp[j] = f2bf(W[(size_t)(kbase + j) * Hh + col]);
    *(uint4*)(Wp + (size_t)t * 8) = *(const uint4*)tmp;
}

// type_bias[t][col] = b_enc[col] + sum_k ett[t][k] * Wenc[256+k][col]
__global__ __launch_bounds__(256) void k_prep_tb(const float* __restrict__ ett,
                                                 const float* __restrict__ Wenc,
                                                 const float* __restrict__ benc,
                                                 float* __restrict__ tb) {
    __shared__ float s_e[NTy * TEe];
    int tid = threadIdx.x;
    for (int i = tid; i < NTy * TEe; i += 256) s_e[i] = ett[i];
    __syncthreads();
    float b = benc[tid];
    for (int t = 0; t < NTy; t++) {
        float acc = b;
        #pragma unroll 8
        for (int k = 0; k < TEe; k++)
            acc = fmaf(s_e[t * TEe + k], Wenc[(size_t)(Hh + k) * Hh + tid], acc);
        tb[t * Hh + tid] = acc;
    }
}

__global__ void k_count(const int* __restrict__ members, const void* __restrict__ maskp,
                        const int* __restrict__ flagp, int* __restrict__ deg) {
    int flag = flagp[0];
    for (int i = blockIdx.x * blockDim.x + threadIdx.x; i < BE * Aa;
         i += gridDim.x * blockDim.x) {
        if (mask_at(maskp, flag, i) != 0.f) {
            int ge = i >> 3;
            int b = ge / Ee;
            int idx = min(max(members[i], 0), Nn - 1);
            atomicAdd(&deg[b * Nn + idx], 1);
        }
    }
}

__global__ __launch_bounds__(SCB) void k_scan_blk(const int* __restrict__ deg,
                                                  int* __restrict__ iscan,
                                                  int* __restrict__ bsums) {
    __shared__ int sm[SCB];
    int t = threadIdx.x;
    int j = blockIdx.x * SCB + t;
    sm[t] = (j < BN) ? deg[j] : 0;
    __syncthreads();
    for (int d = 1; d < SCB; d <<= 1) {
        int x = (t >= d) ? sm[t - d] : 0;
        __syncthreads();
        sm[t] += x;
        __syncthreads();
    }
    if (j < BN) iscan[j] = sm[t];
    if (t == SCB - 1) bsums[blockIdx.x] = sm[SCB - 1];
}

// fused: per-block redundant 64-lane scan of block sums, then offs/cur
__global__ __launch_bounds__(256) void k_scan_add(const int* __restrict__ iscan,
                                                  const int* __restrict__ deg,
                                                  const int* __restrict__ bsums,
                                                  int* __restrict__ offs,
                                                  int* __restrict__ cur) {
    __shared__ int sb[64];
    int tid = threadIdx.x;
    if (tid < 64) {
        int v0 = (tid < NSB) ? bsums[tid] : 0;
        int v = v0;
        #pragma unroll
        for (int d = 1; d < 64; d <<= 1) {
            int x = __shfl_up(v, d, 64);
            if (tid >= d) v += x;
        }
        sb[tid] = v - v0;   // exclusive
        if (blockIdx.x == 0 && tid == 63) offs[BN] = v;  // grand total
    }
    __syncthreads();
    int j = blockIdx.x * 256 + tid;
    if (j < BN) {
        int o = iscan[j] - deg[j] + sb[j >> 10];
        offs[j] = o;
        cur[j]  = o;
    }
}

__global__ void k_fill(const int* __restrict__ members, const void* __restrict__ maskp,
                       const int* __restrict__ flagp, int* __restrict__ cur,
                       int* __restrict__ list) {
    int flag = flagp[0];
    for (int i = blockIdx.x * blockDim.x + threadIdx.x; i < BE * Aa;
         i += gridDim.x * blockDim.x) {
        if (mask_at(maskp, flag, i) != 0.f) {
            int ge = i >> 3;
            int b = ge / Ee;
            int idx = min(max(members[i], 0), Nn - 1);
            int pos = atomicAdd(&cur[b * Nn + idx], 1);
            list[pos] = ge;
        }
    }
}

// -------- Edge pooling gather: one wave per edge --------
template <bool NFBF>
__global__ __launch_bounds__(512) void k_gath_edge(
    const float* __restrict__ nf, const u16* __restrict__ nfb,
    const int* __restrict__ members, const void* __restrict__ maskp,
    const int* __restrict__ flagp, u16* __restrict__ pooled) {
    const int e = (blockIdx.x * 512 + threadIdx.x) >> 6;
    const int lane = threadIdx.x & 63;
    if (e >= BE) return;
    const int flag = flagp[0];

    int mem = 0; float mv = 0.f;
    if (lane < Aa) {
        int gi = e * Aa + lane;
        mem = min(max(members[gi], 0), Nn - 1) + ((e >= Ee) ? Nn : 0);
        mv = mask_at(maskp, flag, gi);
    }
    int idx[Aa]; float m[Aa];
    #pragma unroll
    for (int a = 0; a < Aa; a++) {
        idx[a] = __shfl(mem, a, 64);
        m[a]   = __shfl(mv, a, 64);
    }
    float c = 0.f;
    #pragma unroll
    for (int a = 0; a < Aa; a++) c += m[a];
    const float rc = 1.f / fmaxf(c, 1.f);

    const int c4 = lane * 4;
    float a0 = 0.f, a1 = 0.f, a2 = 0.f, a3 = 0.f;
    if (NFBF) {
        ushort4 v[Aa];
        #pragma unroll
        for (int a = 0; a < Aa; a++)
            v[a] = *(const ushort4*)(nfb + (size_t)idx[a] * Hh + c4);
        #pragma unroll
        for (int a = 0; a < Aa; a++) {
            a0 = fmaf(m[a], bf2f(v[a].x), a0);
            a1 = fmaf(m[a], bf2f(v[a].y), a1);
            a2 = fmaf(m[a], bf2f(v[a].z), a2);
            a3 = fmaf(m[a], bf2f(v[a].w), a3);
        }
    } else {
        float4 v[Aa];
        #pragma unroll
        for (int a = 0; a < Aa; a++)
            v[a] = *(const float4*)(nf + (size_t)idx[a] * Hh + c4);
        #pragma unroll
        for (int a = 0; a < Aa; a++) {
            a0 = fmaf(m[a], v[a].x, a0);
            a1 = fmaf(m[a], v[a].y, a1);
            a2 = fmaf(m[a], v[a].z, a2);
            a3 = fmaf(m[a], v[a].w, a3);
        }
    }
    ushort4 o;
    o.x = f2bf(a0 * rc); o.y = f2bf(a1 * rc);
    o.z = f2bf(a2 * rc); o.w = f2bf(a3 * rc);
    *(ushort4*)(pooled + (size_t)e * Hh + c4) = o;
}

// -------- Node update gather: one wave per node --------
__global__ __launch_bounds__(512) void k_gath_node(
    const u16* __restrict__ efb, const int* __restrict__ offs,
    const int* __restrict__ list, u16* __restrict__ updb) {
    const int n = (blockIdx.x * 512 + threadIdx.x) >> 6;
    const int lane = threadIdx.x & 63;
    if (n >= BN) return;
    const int o0 = offs[n];
    const int d  = offs[n + 1] - o0;
    const int c4 = lane * 4;
    float a0 = 0.f, a1 = 0.f, a2 = 0.f, a3 = 0.f;
    for (int j0 = 0; j0 < d; j0 += 8) {
        int lv = (lane < 8 && (j0 + lane) < d) ? list[o0 + j0 + lane] : BE;
        ushort4 v[8];
        #pragma unroll
        for (int q = 0; q < 8; q++) {
            int ge = __shfl(lv, q, 64);
            v[q] = *(const ushort4*)(efb + (size_t)ge * Hh + c4);
        }
        #pragma unroll
        for (int q = 0; q < 8; q++) {
            a0 += bf2f(v[q].x); a1 += bf2f(v[q].y);
            a2 += bf2f(v[q].z); a3 += bf2f(v[q].w);
        }
    }
    const float rc = 1.f / fmaxf((float)d, 1.f);
    ushort4 o;
    o.x = f2bf(a0 * rc); o.y = f2bf(a1 * rc);
    o.z = f2bf(a2 * rc); o.w = f2bf(a3 * rc);
    *(ushort4*)(updb + (size_t)n * Hh + c4) = o;
}

// -------- Edge GEMM: BM=64, 512 threads, no A-LDS (A direct from L2) --------
__global__ __launch_bounds__(512) void k_gemm_edge(
    const u16* __restrict__ pooled, const int* __restrict__ types,
    const bf16x8* __restrict__ Wp, const float* __restrict__ tb,
    const float* __restrict__ genc, const float* __restrict__ beenc,
    u16* __restrict__ efb) {
    __shared__ float s_red[64][4], s_red2[64][4];
    __shared__ float s_stats[64][2];

    const int tid = threadIdx.x;
    const int e0  = blockIdx.x * 64;
    const int w = tid >> 6, lane = tid & 63;
    const int wr = w >> 2, wc = w & 3;
    const int l15 = lane & 15, lg = lane >> 4;

    f32x4 acc[2][4];
    #pragma unroll
    for (int m = 0; m < 2; m++)
        #pragma unroll
        for (int n = 0; n < 4; n++) acc[m][n] = (f32x4){0.f, 0.f, 0.f, 0.f};

    const u16* A0 = pooled + (size_t)(e0 + wr * 32 + l15) * Hh + lg * 8;
    #pragma unroll
    for (int kt = 0; kt < KTE; kt++) {
        bf16x8 bfr[4], afr[2];
        #pragma unroll
        for (int n = 0; n < 4; n++)
            bfr[n] = Wp[((size_t)((wc * 4 + n) * KTE + kt)) * 64 + lane];
        #pragma unroll
        for (int m = 0; m < 2; m++)
            afr[m] = *(const bf16x8*)(A0 + (size_t)m * 16 * Hh + kt * 32);
        #pragma unroll
        for (int m = 0; m < 2; m++)
            #pragma unroll
            for (int n = 0; n < 4; n++)
                acc[m][n] = mfma16(afr[m], bfr[n], acc[m][n]);
    }

    // + type_bias, gelu
    #pragma unroll
    for (int m = 0; m < 2; m++)
        #pragma unroll
        for (int j = 0; j < 4; j++) {
            int r = wr * 32 + m * 16 + lg * 4 + j;
            int t = types[e0 + r];
            #pragma unroll
            for (int n = 0; n < 4; n++) {
                int col = wc * 64 + n * 16 + l15;
                acc[m][n][j] = gelu_f(acc[m][n][j] + tb[t * Hh + col]);
            }
        }

    #pragma unroll
    for (int m = 0; m < 2; m++)
        #pragma unroll
        for (int j = 0; j < 4; j++) {
            float s = 0.f, s2 = 0.f;
            #pragma unroll
            for (int n = 0; n < 4; n++) {
                float v = acc[m][n][j];
                s += v; s2 = fmaf(v, v, s2);
            }
            #pragma unroll
            for (int mk = 1; mk < 16; mk <<= 1) {
                s  += __shfl_xor(s, mk, 64);
                s2 += __shfl_xor(s2, mk, 64);
            }
            if (l15 == 0) {
                int r = wr * 32 + m * 16 + lg * 4 + j;
                s_red[r][wc] = s; s_red2[r][wc] = s2;
            }
        }
    __syncthreads();
    if (tid < 64) {
        float s  = s_red[tid][0] + s_red[tid][1] + s_red[tid][2] + s_red[tid][3];
        float s2 = s_red2[tid][0] + s_red2[tid][1] + s_red2[tid][2] + s_red2[tid][3];
        float mu = s * (1.f / Hh);
        float var = s2 * (1.f / Hh) - mu * mu;
        s_stats[tid][0] = mu;
        s_stats[tid][1] = rsqrtf(var + 1e-5f);
    }
    __syncthreads();
    float gam[4], bet[4];
    #pragma unroll
    for (int n = 0; n < 4; n++) {
        int col = wc * 64 + n * 16 + l15;
        gam[n] = genc[col]; bet[n] = beenc[col];
    }
    #pragma unroll
    for (int m = 0; m < 2; m++)
        #pragma unroll
        for (int j = 0; j < 4; j++) {
            int r = wr * 32 + m * 16 + lg * 4 + j;
            float mu = s_stats[r][0], rs = s_stats[r][1];
            u16* dst = efb + (size_t)(e0 + r) * Hh + wc * 64 + l15;
            #pragma unroll
            for (int n = 0; n < 4; n++) {
                float val = (acc[m][n][j] - mu) * rs * gam[n] + bet[n];
                dst[n * 16] = f2bf(val);
            }
        }
}

// -------- Node GEMM: BM=64, 512 threads, no A-LDS --------
template <bool NFBF>
__global__ __launch_bounds__(512) void k_gemm_node(
    const float* __restrict__ nf, const u16* __restrict__ nfb,
    const u16* __restrict__ updb, const bf16x8* __restrict__ Wp,
    const float* __restrict__ bupd, const float* __restrict__ gupd,
    const float* __restrict__ beupd, float* __restrict__ out) {
    __shared__ float s_red[64][4], s_red2[64][4];
    __shared__ float s_stats[64][2];

    const int tid = threadIdx.x;
    const int n0  = blockIdx.x * 64;
    const int w = tid >> 6, lane = tid & 63;
    const int wr = w >> 2, wc = w & 3;
    const int l15 = lane & 15, lg = lane >> 4;

    f32x4 acc[2][4];
    #pragma unroll
    for (int m = 0; m < 2; m++)
        #pragma unroll
        for (int n = 0; n < 4; n++) acc[m][n] = (f32x4){0.f, 0.f, 0.f, 0.f};

    const size_t rbase = (size_t)(n0 + wr * 32 + l15) * Hh + lg * 8;
    const u16* A1b = nfb + rbase;
    const float* A1f = nf + rbase;
    const u16* A2 = updb + rbase;

    // K-half 1: nf cols 0..255 (kt 0..7)
    #pragma unroll
    for (int kt = 0; kt < 8; kt++) {
        bf16x8 bfr[4], afr[2];
        #pragma unroll
        for (int n = 0; n < 4; n++)
            bfr[n] = Wp[((size_t)((wc * 4 + n) * KTU + kt)) * 64 + lane];
        #pragma unroll
        for (int m = 0; m < 2; m++) {
            if (NFBF) {
                afr[m] = *(const bf16x8*)(A1b + (size_t)m * 16 * Hh + kt * 32);
            } else {
                const float* src = A1f + (size_t)m * 16 * Hh + kt * 32;
                float4 v0 = *(const float4*)src;
                float4 v1 = *(const float4*)(src + 4);
                u16 t[8];
                t[0]=f2bf(v0.x); t[1]=f2bf(v0.y); t[2]=f2bf(v0.z); t[3]=f2bf(v0.w);
                t[4]=f2bf(v1.x); t[5]=f2bf(v1.y); t[6]=f2bf(v1.z); t[7]=f2bf(v1.w);
                afr[m] = *(const bf16x8*)t;
            }
        }
        #pragma unroll
        for (int m = 0; m < 2; m++)
            #pragma unroll
            for (int n = 0; n < 4; n++)
                acc[m][n] = mfma16(afr[m], bfr[n], acc[m][n]);
    }
    // K-half 2: updb cols 0..255 (kt 8..15)
    #pragma unroll
    for (int kt = 8; kt < 16; kt++) {
        bf16x8 bfr[4], afr[2];
        #pragma unroll
        for (int n = 0; n < 4; n++)
            bfr[n] = Wp[((size_t)((wc * 4 + n) * KTU + kt)) * 64 + lane];
        #pragma unroll
        for (int m = 0; m < 2; m++)
            afr[m] = *(const bf16x8*)(A2 + (size_t)m * 16 * Hh + (kt - 8) * 32);
        #pragma unroll
        for (int m = 0; m < 2; m++)
            #pragma unroll
            for (int n = 0; n < 4; n++)
                acc[m][n] = mfma16(afr[m], bfr[n], acc[m][n]);
    }

    float bia[4], gam[4], bet[4];
    #pragma unroll
    for (int n = 0; n < 4; n++) bia[n] = bupd[wc * 64 + n * 16 + l15];
    #pragma unroll
    for (int m = 0; m < 2; m++)
        #pragma unroll
        for (int n = 0; n < 4; n++)
            #pragma unroll
            for (int j = 0; j < 4; j++)
                acc[m][n][j] = gelu_f(acc[m][n][j] + bia[n]);

    #pragma unroll
    for (int m = 0; m < 2; m++)
        #pragma unroll
        for (int j = 0; j < 4; j++) {
            float s = 0.f, s2 = 0.f;
            #pragma unroll
            for (int n = 0; n < 4; n++) {
                float v = acc[m][n][j];
                s += v; s2 = fmaf(v, v, s2);
            }
            #pragma unroll
            for (int mk = 1; mk < 16; mk <<= 1) {
                s  += __shfl_xor(s, mk, 64);
                s2 += __shfl_xor(s2, mk, 64);
            }
            if (l15 == 0) {
                int r = wr * 32 + m * 16 + lg * 4 + j;
                s_red[r][wc] = s; s_red2[r][wc] = s2;
            }
        }
    __syncthreads();
    if (tid < 64) {
        float s  = s_red[tid][0] + s_red[tid][1] + s_red[tid][2] + s_red[tid][3];
        float s2 = s_red2[tid][0] + s_red2[tid][1] + s_red2[tid][2] + s_red2[tid][3];
        float mu = s * (1.f / Hh);
        float var = s2 * (1.f / Hh) - mu * mu;
        s_stats[tid][0] = mu;
        s_stats[tid][1] = rsqrtf(var + 1e-5f);
    }
    __syncthreads();
    #pragma unroll
    for (int n = 0; n < 4; n++) {
        int col = wc * 64 + n * 16 + l15;
        gam[n] = gupd[col]; bet[n] = beupd[col];
    }
    #pragma unroll
    for (int m = 0; m < 2; m++)
        #pragma unroll
        for (int j = 0; j < 4; j++) {
            int r = wr * 32 + m * 16 + lg * 4 + j;
            float mu = s_stats[r][0], rs = s_stats[r][1];
            float* dst = out + (size_t)(n0 + r) * Hh + wc * 64 + l15;
            #pragma unroll
            for (int n = 0; n < 4; n++) {
                float val = (acc[m][n][j] - mu) * rs * gam[n] + bet[n];
                dst[n * 16] = val;
            }
        }
}

extern "C" void kernel_launch(void* const* d_in, const int* in_sizes, int n_in,
                              void* d_out, int out_size, void* d_ws, size_t ws_size,
                              hipStream_t stream) {
    const float* nf    = (const float*)d_in[0];
    const int* members = (const int*)d_in[1];
    const int* types   = (const int*)d_in[2];
    const void* maskp  = d_in[3];
    const float* ett   = (const float*)d_in[4];
    const float* Wenc  = (const float*)d_in[5];
    const float* benc  = (const float*)d_in[6];
    const float* genc  = (const float*)d_in[7];
    const float* beenc = (const float*)d_in[8];
    const float* Wupd  = (const float*)d_in[9];
    const float* bupd  = (const float*)d_in[10];
    const float* gupd  = (const float*)d_in[11];
    const float* beupd = (const float*)d_in[12];
    float* out = (float*)d_out;

    // workspace layout
    int* ip    = (int*)d_ws;
    int* flag  = ip;                      // 64 ints
    int* deg   = ip + 64;                 // BN
    int* offs  = deg + BN;                // BN+16
    int* cur   = offs + BN + 16;          // BN
    int* iscan = cur + BN;                // BN
    int* bsums = iscan + BN;              // 64
    int* list  = bsums + 64;              // BE*Aa + 16
    char* p    = (char*)(list + BE * Aa + 16);
    u16* efb   = (u16*)p;   p += (size_t)(BE + 1) * Hh * 2;   // 20.5 MB (+zero row)
    u16* pool  = (u16*)p;   p += (size_t)BE * Hh * 2;         // 20.5 MB (shared w/ updb)
    u16* updb  = pool;                                        // disjoint lifetime
    u16* We1P  = (u16*)p;   p += (size_t)16 * KTE * 64 * 8 * 2;   // 131 KB
    u16* WupdP = (u16*)p;   p += (size_t)16 * KTU * 64 * 8 * 2;   // 262 KB
    float* tb  = (float*)p; p += (size_t)NTy * Hh * 4;            // 16 KB
    u16* nfb   = (u16*)p;   p += (size_t)BN * Hh * 2;             // 20.5 MB (optional)
    const bool use_nfbf = ((size_t)(p - (char*)d_ws) <= ws_size);

    int n4 = (64 + BN) / 4;
    hipLaunchKernelGGL(k_zero2, dim3(64), dim3(256), 0, stream,
                       (float4*)ip, n4,
                       (float4*)(efb + (size_t)BE * Hh), Hh * 2 / 16);
    hipLaunchKernelGGL(k_detect, dim3(256), dim3(256), 0, stream,
                       (const unsigned int*)maskp, BE * Aa / 4, flag);
    if (use_nfbf)
        hipLaunchKernelGGL(k_cvt, dim3(2048), dim3(256), 0, stream,
                           (const float4*)nf, (ushort4*)nfb, BN * Hh / 4);
    hipLaunchKernelGGL(k_pack, dim3(32), dim3(256), 0, stream,
                       Wenc, We1P, KTE, 16 * KTE * 64);
    hipLaunchKernelGGL(k_pack, dim3(64), dim3(256), 0, stream,
                       Wupd, WupdP, KTU, 16 * KTU * 64);
    hipLaunchKernelGGL(k_prep_tb, dim3(1), dim3(256), 0, stream,
                       ett, Wenc, benc, tb);
    hipLaunchKernelGGL(k_count, dim3(640), dim3(256), 0, stream,
                       members, maskp, flag, deg);
    hipLaunchKernelGGL(k_scan_blk, dim3(NSB), dim3(SCB), 0, stream,
                       deg, iscan, bsums);
    hipLaunchKernelGGL(k_scan_add, dim3((BN + 255) / 256), dim3(256), 0, stream,
                       iscan, deg, bsums, offs, cur);
    hipLaunchKernelGGL(k_fill, dim3(640), dim3(256), 0, stream,
                       members, maskp, flag, cur, list);
    if (use_nfbf)
        hipLaunchKernelGGL((k_gath_edge<true>), dim3(BE * 64 / 512), dim3(512), 0,
                           stream, nf, nfb, members, maskp, flag, pool);
    else
        hipLaunchKernelGGL((k_gath_edge<false>), dim3(BE * 64 / 512), dim3(512), 0,
                           stream, nf, nfb, members, maskp, flag, pool);
    hipLaunchKernelGGL(k_gemm_edge, dim3(BE / 64), dim3(512), 0, stream,
                       pool, types, (const bf16x8*)We1P, tb, genc, beenc, efb);
    hipLaunchKernelGGL(k_gath_node, dim3(BN * 64 / 512), dim3(512), 0, stream,
                       efb, offs, list, updb);
    if (use_nfbf)
        hipLaunchKernelGGL((k_gemm_node<true>), dim3(BN / 64), dim3(512), 0, stream,
                           nf, nfb, updb, (const bf16x8*)WupdP,
                           bupd, gupd, beupd, out);
    else
        hipLaunchKernelGGL((k_gemm_node<false>), dim3(BN / 64), dim3(512), 0, stream,
                           nf, nfb, updb, (const bf16x8*)WupdP,
                           bupd, gupd, beupd, out);
}

// Round 9
// 176.043 us; speedup vs baseline: 1.1366x; 1.1366x over previous
//
#include <hip/hip_runtime.h>
#include <math.h>

// Problem constants
#define Bq 2
#define Nn 20000
#define Ee 20000
#define Aa 8
#define Hh 256
#define TEe 32
#define NTy 16
constexpr int BE   = Bq * Ee;    // 40000
constexpr int BN   = Bq * Nn;    // 40000
constexpr int KTE  = 8;          // edge GEMM K-tiles (256/32)
constexpr int KTU  = 16;         // node GEMM K-tiles (512/32)
constexpr int LDA  = 264;        // padded A row (ushorts) = 33 uint4
constexpr int SCB  = 1024;       // scan block size
constexpr int NSB  = (BN + SCB - 1) / SCB;   // 40
// k_prep block partition
constexpr int PB_CVT  = 2048;
constexpr int PB_PKE  = 32;      // 16*KTE*64 / 256
constexpr int PB_PKU  = 64;      // 16*KTU*64 / 256
constexpr int PB_TB   = 1;
constexpr int PB_CNT  = 640;
constexpr int NPREP   = PB_CVT + PB_PKE + PB_PKU + PB_TB + PB_CNT;

typedef __attribute__((ext_vector_type(8))) short bf16x8;
typedef __attribute__((ext_vector_type(4))) float f32x4;
typedef unsigned short u16;
typedef unsigned int   u32;

__device__ __forceinline__ u16 f2bf(float f) {           // RNE f32 -> bf16
    u32 u = __float_as_uint(f);
    u32 r = u + 0x7FFFu + ((u >> 16) & 1u);
    return (u16)(r >> 16);
}
__device__ __forceinline__ float bf2f(u16 h) {
    return __uint_as_float(((u32)h) << 16);
}
__device__ __forceinline__ float gelu_f(float x) {
    return 0.5f * x * (1.f + erff(x * 0.70710678118654752440f));
}
__device__ __forceinline__ f32x4 mfma16(bf16x8 a, bf16x8 b, f32x4 c) {
    return __builtin_amdgcn_mfma_f32_16x16x32_bf16(a, b, c, 0, 0, 0);
}

// mask dtype sniffing: bit1 => f32 mask, bit0 => u8 mask, none => i32
__device__ __forceinline__ float mask_at(const void* mp, int flag, int i) {
    if (flag & 2) return ((const float*)mp)[i];
    if (flag & 1) return ((const unsigned char*)mp)[i] ? 1.f : 0.f;
    return ((const int*)mp)[i] ? 1.f : 0.f;
}

__global__ void k_detect(const unsigned int* mw, int n, int* flag) {
    int found = 0;
    for (int i = blockIdx.x * blockDim.x + threadIdx.x; i < n;
         i += gridDim.x * blockDim.x) {
        unsigned int w = mw[i];
        if (w == 0x3F800000u) found |= 2;
        else if (w > 1u) found |= 1;
    }
    __shared__ int sf;
    if (threadIdx.x == 0) sf = 0;
    __syncthreads();
    if (found) atomicOr(&sf, found);
    __syncthreads();
    if (threadIdx.x == 0 && sf) atomicOr(flag, sf);
}

// fused prep: cvt | pack(Wenc) | pack(Wupd) | type_bias | count
__global__ __launch_bounds__(256) void k_prep(
    const float4* __restrict__ nf4, ushort4* __restrict__ nfb4, int donf,
    const float* __restrict__ Wenc, u16* __restrict__ WeP,
    const float* __restrict__ Wupd, u16* __restrict__ WuP,
    const float* __restrict__ ett, const float* __restrict__ benc,
    float* __restrict__ tb,
    const int* __restrict__ members, const void* __restrict__ maskp,
    const int* __restrict__ flagp, int* __restrict__ deg) {
    __shared__ float s_e[NTy * TEe];
    const int bid = blockIdx.x;
    const int tid = threadIdx.x;

    if (bid < PB_CVT) {                       // ---- cvt nf -> bf16
        if (!donf) return;
        int n4 = BN * Hh / 4;
        for (int i = bid * 256 + tid; i < n4; i += PB_CVT * 256) {
            float4 v = nf4[i];
            ushort4 u;
            u.x = f2bf(v.x); u.y = f2bf(v.y); u.z = f2bf(v.z); u.w = f2bf(v.w);
            nfb4[i] = u;
        }
    } else if (bid < PB_CVT + PB_PKE) {       // ---- pack Wenc
        int t = (bid - PB_CVT) * 256 + tid;
        int lane = t & 63, tile = t >> 6;
        int kt = tile % KTE, nt = tile / KTE;
        int kbase = kt * 32 + (lane >> 4) * 8;
        int col = nt * 16 + (lane & 15);
        u16 tmp[8];
        #pragma unroll
        for (int j = 0; j < 8; j++)
            tmp[j] = f2bf(Wenc[(size_t)(kbase + j) * Hh + col]);
        *(uint4*)(WeP + (size_t)t * 8) = *(const uint4*)tmp;
    } else if (bid < PB_CVT + PB_PKE + PB_PKU) {   // ---- pack Wupd
        int t = (bid - PB_CVT - PB_PKE) * 256 + tid;
        int lane = t & 63, tile = t >> 6;
        int kt = tile % KTU, nt = tile / KTU;
        int kbase = kt * 32 + (lane >> 4) * 8;
        int col = nt * 16 + (lane & 15);
        u16 tmp[8];
        #pragma unroll
        for (int j = 0; j < 8; j++)
            tmp[j] = f2bf(Wupd[(size_t)(kbase + j) * Hh + col]);
        *(uint4*)(WuP + (size_t)t * 8) = *(const uint4*)tmp;
    } else if (bid < PB_CVT + PB_PKE + PB_PKU + PB_TB) {   // ---- type_bias
        for (int i = tid; i < NTy * TEe; i += 256) s_e[i] = ett[i];
        __syncthreads();
        float b = benc[tid];
        for (int t = 0; t < NTy; t++) {
            float acc = b;
            #pragma unroll 8
            for (int k = 0; k < TEe; k++)
                acc = fmaf(s_e[t * TEe + k], Wenc[(size_t)(Hh + k) * Hh + tid], acc);
            tb[t * Hh + tid] = acc;
        }
    } else {                                   // ---- count degrees
        int flag = flagp[0];
        int cbid = bid - (PB_CVT + PB_PKE + PB_PKU + PB_TB);
        for (int i = cbid * 256 + tid; i < BE * Aa; i += PB_CNT * 256) {
            if (mask_at(maskp, flag, i) != 0.f) {
                int ge = i >> 3;
                int b = ge / Ee;
                int idx = min(max(members[i], 0), Nn - 1);
                atomicAdd(&deg[b * Nn + idx], 1);
            }
        }
    }
}

__global__ __launch_bounds__(SCB) void k_scan_blk(const int* __restrict__ deg,
                                                  int* __restrict__ iscan,
                                                  int* __restrict__ bsums) {
    __shared__ int sm[SCB];
    int t = threadIdx.x;
    int j = blockIdx.x * SCB + t;
    sm[t] = (j < BN) ? deg[j] : 0;
    __syncthreads();
    for (int d = 1; d < SCB; d <<= 1) {
        int x = (t >= d) ? sm[t - d] : 0;
        __syncthreads();
        sm[t] += x;
        __syncthreads();
    }
    if (j < BN) iscan[j] = sm[t];
    if (t == SCB - 1) bsums[blockIdx.x] = sm[SCB - 1];
}

// fused: per-block redundant 64-lane scan of block sums, then offs/cur
__global__ __launch_bounds__(256) void k_scan_add(const int* __restrict__ iscan,
                                                  const int* __restrict__ deg,
                                                  const int* __restrict__ bsums,
                                                  int* __restrict__ offs,
                                                  int* __restrict__ cur) {
    __shared__ int sb[64];
    int tid = threadIdx.x;
    if (tid < 64) {
        int v0 = (tid < NSB) ? bsums[tid] : 0;
        int v = v0;
        #pragma unroll
        for (int d = 1; d < 64; d <<= 1) {
            int x = __shfl_up(v, d, 64);
            if (tid >= d) v += x;
        }
        sb[tid] = v - v0;   // exclusive
        if (blockIdx.x == 0 && tid == 63) offs[BN] = v;  // grand total
    }
    __syncthreads();
    int j = blockIdx.x * 256 + tid;
    if (j < BN) {
        int o = iscan[j] - deg[j] + sb[j >> 10];
        offs[j] = o;
        cur[j]  = o;
    }
}

__global__ void k_fill(const int* __restrict__ members, const void* __restrict__ maskp,
                       const int* __restrict__ flagp, int* __restrict__ cur,
                       int* __restrict__ list) {
    int flag = flagp[0];
    for (int i = blockIdx.x * blockDim.x + threadIdx.x; i < BE * Aa;
         i += gridDim.x * blockDim.x) {
        if (mask_at(maskp, flag, i) != 0.f) {
            int ge = i >> 3;
            int b = ge / Ee;
            int idx = min(max(members[i], 0), Nn - 1);
            int pos = atomicAdd(&cur[b * Nn + idx], 1);
            list[pos] = ge;
        }
    }
}

// -------- Edge GEMM, fused gather: BM=64, 512 threads, 8 waves --------
template <bool NFBF>
__global__ __launch_bounds__(512) void k_gemm_edge(
    const float* __restrict__ nf, const u16* __restrict__ nfb,
    const int* __restrict__ members, const int* __restrict__ types,
    const void* __restrict__ maskp, const int* __restrict__ flagp,
    const bf16x8* __restrict__ Wp, const float* __restrict__ tb,
    const float* __restrict__ genc, const float* __restrict__ beenc,
    uint4* __restrict__ ef4) {
    __shared__ __align__(16) u16 s_a[64][LDA];   // 33.8 KB
    __shared__ float s_red[64][4], s_red2[64][4];
    __shared__ float s_stats[64][2];

    const int tid = threadIdx.x;
    const int e0  = blockIdx.x * 64;
    const int w = tid >> 6, lane = tid & 63;
    const int wr = w >> 2, wc = w & 3;
    const int l15 = lane & 15, lg = lane >> 4;
    const int flag = flagp[0];
    const int c4 = lane * 4;

    // gather pooled rows: wave w owns rows w*8 .. w*8+7
    for (int i = 0; i < 8; i++) {
        int r = w * 8 + i;
        int e = e0 + r;
        int mem = 0; float mv = 0.f;
        if (lane < Aa) {
            int gi = e * Aa + lane;
            mem = min(max(members[gi], 0), Nn - 1) + ((e >= Ee) ? Nn : 0);
            mv = mask_at(maskp, flag, gi);
        }
        int idx[Aa]; float m[Aa];
        float c = 0.f;
        #pragma unroll
        for (int a = 0; a < Aa; a++) {
            idx[a] = __shfl(mem, a, 64);
            m[a]   = __shfl(mv, a, 64);
            c += m[a];
        }
        const float rc = 1.f / fmaxf(c, 1.f);
        float a0 = 0.f, a1 = 0.f, a2 = 0.f, a3 = 0.f;
        if (NFBF) {
            ushort4 v[Aa];
            #pragma unroll
            for (int a = 0; a < Aa; a++)
                v[a] = *(const ushort4*)(nfb + (size_t)idx[a] * Hh + c4);
            #pragma unroll
            for (int a = 0; a < Aa; a++) {
                a0 = fmaf(m[a], bf2f(v[a].x), a0);
                a1 = fmaf(m[a], bf2f(v[a].y), a1);
                a2 = fmaf(m[a], bf2f(v[a].z), a2);
                a3 = fmaf(m[a], bf2f(v[a].w), a3);
            }
        } else {
            float4 v[Aa];
            #pragma unroll
            for (int a = 0; a < Aa; a++)
                v[a] = *(const float4*)(nf + (size_t)idx[a] * Hh + c4);
            #pragma unroll
            for (int a = 0; a < Aa; a++) {
                a0 = fmaf(m[a], v[a].x, a0);
                a1 = fmaf(m[a], v[a].y, a1);
                a2 = fmaf(m[a], v[a].z, a2);
                a3 = fmaf(m[a], v[a].w, a3);
            }
        }
        ushort4 o;
        o.x = f2bf(a0 * rc); o.y = f2bf(a1 * rc);
        o.z = f2bf(a2 * rc); o.w = f2bf(a3 * rc);
        *(ushort4*)&s_a[r][c4] = o;
    }
    __syncthreads();

    f32x4 acc[2][4];
    #pragma unroll
    for (int m = 0; m < 2; m++)
        #pragma unroll
        for (int n = 0; n < 4; n++) acc[m][n] = (f32x4){0.f, 0.f, 0.f, 0.f};

    #pragma unroll
    for (int kt = 0; kt < KTE; kt++) {
        bf16x8 bfr[4], afr[2];
        #pragma unroll
        for (int n = 0; n < 4; n++)
            bfr[n] = Wp[((size_t)((wc * 4 + n) * KTE + kt)) * 64 + lane];
        #pragma unroll
        for (int m = 0; m < 2; m++)
            afr[m] = *(const bf16x8*)&s_a[wr * 32 + m * 16 + l15][kt * 32 + lg * 8];
        #pragma unroll
        for (int m = 0; m < 2; m++)
            #pragma unroll
            for (int n = 0; n < 4; n++)
                acc[m][n] = mfma16(afr[m], bfr[n], acc[m][n]);
    }

    // + type_bias, gelu
    #pragma unroll
    for (int m = 0; m < 2; m++)
        #pragma unroll
        for (int j = 0; j < 4; j++) {
            int r = wr * 32 + m * 16 + lg * 4 + j;
            int t = types[e0 + r];
            #pragma unroll
            for (int n = 0; n < 4; n++) {
                int col = wc * 64 + n * 16 + l15;
                acc[m][n][j] = gelu_f(acc[m][n][j] + tb[t * Hh + col]);
            }
        }

    #pragma unroll
    for (int m = 0; m < 2; m++)
        #pragma unroll
        for (int j = 0; j < 4; j++) {
            float s = 0.f, s2 = 0.f;
            #pragma unroll
            for (int n = 0; n < 4; n++) {
                float v = acc[m][n][j];
                s += v; s2 = fmaf(v, v, s2);
            }
            #pragma unroll
            for (int mk = 1; mk < 16; mk <<= 1) {
                s  += __shfl_xor(s, mk, 64);
                s2 += __shfl_xor(s2, mk, 64);
            }
            if (l15 == 0) {
                int r = wr * 32 + m * 16 + lg * 4 + j;
                s_red[r][wc] = s; s_red2[r][wc] = s2;
            }
        }
    __syncthreads();
    if (tid < 64) {
        float s  = s_red[tid][0] + s_red[tid][1] + s_red[tid][2] + s_red[tid][3];
        float s2 = s_red2[tid][0] + s_red2[tid][1] + s_red2[tid][2] + s_red2[tid][3];
        float mu = s * (1.f / Hh);
        float var = s2 * (1.f / Hh) - mu * mu;
        s_stats[tid][0] = mu;
        s_stats[tid][1] = rsqrtf(var + 1e-5f);
    }
    __syncthreads();
    float gam[4], bet[4];
    #pragma unroll
    for (int n = 0; n < 4; n++) {
        int col = wc * 64 + n * 16 + l15;
        gam[n] = genc[col]; bet[n] = beenc[col];
    }
    #pragma unroll
    for (int m = 0; m < 2; m++)
        #pragma unroll
        for (int j = 0; j < 4; j++) {
            int r = wr * 32 + m * 16 + lg * 4 + j;
            float mu = s_stats[r][0], rs = s_stats[r][1];
            #pragma unroll
            for (int n = 0; n < 4; n++) {
                float val = (acc[m][n][j] - mu) * rs * gam[n] + bet[n];
                s_a[r][wc * 64 + n * 16 + l15] = f2bf(val);
            }
        }
    __syncthreads();
    const uint4* sa4 = (const uint4*)&s_a[0][0];   // row stride 33 uint4
    #pragma unroll
    for (int i = 0; i < 4; i++) {
        int idx = i * 512 + tid;
        int r = idx >> 5, cc = idx & 31;
        ef4[(size_t)(e0 + r) * 32 + cc] = sa4[r * 33 + cc];
    }
}

// -------- Node GEMM, fused CSR gather, split-K LDS: BM=64, 512 threads -----
template <bool NFBF>
__global__ __launch_bounds__(512) void k_gemm_node(
    const float* __restrict__ nf, const u16* __restrict__ nfb,
    const u16* __restrict__ efb, const int* __restrict__ offs,
    const int* __restrict__ list, const bf16x8* __restrict__ Wp,
    const float* __restrict__ bupd, const float* __restrict__ gupd,
    const float* __restrict__ beupd, float* __restrict__ out) {
    __shared__ __align__(16) u16 s_a[64][LDA];   // 33.8 KB (K-half buffer)
    __shared__ float s_red[64][4], s_red2[64][4];
    __shared__ float s_stats[64][2];

    const int tid = threadIdx.x;
    const int n0  = blockIdx.x * 64;
    const int w = tid >> 6, lane = tid & 63;
    const int wr = w >> 2, wc = w & 3;
    const int l15 = lane & 15, lg = lane >> 4;
    const int c4 = lane * 4;

    // stage nf half (cols 0..255)
    if (NFBF) {
        uint4* saw = (uint4*)&s_a[0][0];           // row stride 33 uint4
        const uint4* nf4 = (const uint4*)nfb + (size_t)n0 * 32;
        #pragma unroll
        for (int i = 0; i < 4; i++) {
            int idx = i * 512 + tid;
            int r = idx >> 5, cc = idx & 31;
            saw[r * 33 + cc] = nf4[r * 32 + cc];
        }
    } else {
        const float4* nf4 = (const float4*)nf + (size_t)n0 * 64;
        #pragma unroll
        for (int i = 0; i < 8; i++) {
            int idx = i * 512 + tid;
            int r = idx >> 6, cc = idx & 63;
            float4 v = nf4[r * 64 + cc];
            ushort4 u; u.x = f2bf(v.x); u.y = f2bf(v.y);
            u.z = f2bf(v.z); u.w = f2bf(v.w);
            *(ushort4*)&s_a[r][cc * 4] = u;
        }
    }
    __syncthreads();

    f32x4 acc[2][4];
    #pragma unroll
    for (int m = 0; m < 2; m++)
        #pragma unroll
        for (int n = 0; n < 4; n++) acc[m][n] = (f32x4){0.f, 0.f, 0.f, 0.f};

    // K-half 1: nf (kt 0..7)
    #pragma unroll
    for (int kt = 0; kt < 8; kt++) {
        bf16x8 bfr[4], afr[2];
        #pragma unroll
        for (int n = 0; n < 4; n++)
            bfr[n] = Wp[((size_t)((wc * 4 + n) * KTU + kt)) * 64 + lane];
        #pragma unroll
        for (int m = 0; m < 2; m++)
            afr[m] = *(const bf16x8*)&s_a[wr * 32 + m * 16 + l15][kt * 32 + lg * 8];
        #pragma unroll
        for (int m = 0; m < 2; m++)
            #pragma unroll
            for (int n = 0; n < 4; n++)
                acc[m][n] = mfma16(afr[m], bfr[n], acc[m][n]);
    }
    __syncthreads();   // done reading nf half

    // CSR-gather upd half into the same buffer: wave w owns rows w*8..w*8+7
    for (int i = 0; i < 8; i++) {
        int r = w * 8 + i;
        int n = n0 + r;
        int o0 = offs[n];
        int d  = offs[n + 1] - o0;
        float a0 = 0.f, a1 = 0.f, a2 = 0.f, a3 = 0.f;
        for (int j0 = 0; j0 < d; j0 += 8) {
            int lv = (lane < 8 && (j0 + lane) < d) ? list[o0 + j0 + lane] : BE;
            ushort4 v[8];
            #pragma unroll
            for (int q = 0; q < 8; q++) {
                int ge = __shfl(lv, q, 64);
                v[q] = *(const ushort4*)(efb + (size_t)ge * Hh + c4);
            }
            #pragma unroll
            for (int q = 0; q < 8; q++) {
                a0 += bf2f(v[q].x); a1 += bf2f(v[q].y);
                a2 += bf2f(v[q].z); a3 += bf2f(v[q].w);
            }
        }
        const float rc = 1.f / fmaxf((float)d, 1.f);
        ushort4 o;
        o.x = f2bf(a0 * rc); o.y = f2bf(a1 * rc);
        o.z = f2bf(a2 * rc); o.w = f2bf(a3 * rc);
        *(ushort4*)&s_a[r][c4] = o;
    }
    __syncthreads();

    // K-half 2: upd (kt 8..15)
    #pragma unroll
    for (int kt = 8; kt < 16; kt++) {
        bf16x8 bfr[4], afr[2];
        #pragma unroll
        for (int n = 0; n < 4; n++)
            bfr[n] = Wp[((size_t)((wc * 4 + n) * KTU + kt)) * 64 + lane];
        #pragma unroll
        for (int m = 0; m < 2; m++)
            afr[m] = *(const bf16x8*)&s_a[wr * 32 + m * 16 + l15][(kt - 8) * 32 + lg * 8];
        #pragma unroll
        for (int m = 0; m < 2; m++)
            #pragma unroll
            for (int n = 0; n < 4; n++)
                acc[m][n] = mfma16(afr[m], bfr[n], acc[m][n]);
    }

    float bia[4], gam[4], bet[4];
    #pragma unroll
    for (int n = 0; n < 4; n++) bia[n] = bupd[wc * 64 + n * 16 + l15];
    #pragma unroll
    for (int m = 0; m < 2; m++)
        #pragma unroll
        for (int n = 0; n < 4; n++)
            #pragma unroll
            for (int j = 0; j < 4; j++)
                acc[m][n][j] = gelu_f(acc[m][n][j] + bia[n]);

    #pragma unroll
    for (int m = 0; m < 2; m++)
        #pragma unroll
        for (int j = 0; j < 4; j++) {
            float s = 0.f, s2 = 0.f;
            #pragma unroll
            for (int n = 0; n < 4; n++) {
                float v = acc[m][n][j];
                s += v; s2 = fmaf(v, v, s2);
            }
            #pragma unroll
            for (int mk = 1; mk < 16; mk <<= 1) {
                s  += __shfl_xor(s, mk, 64);
                s2 += __shfl_xor(s2, mk, 64);
            }
            if (l15 == 0) {
                int r = wr * 32 + m * 16 + lg * 4 + j;
                s_red[r][wc] = s; s_red2[r][wc] = s2;
            }
        }
    __syncthreads();
    if (tid < 64) {
        float s  = s_red[tid][0] + s_red[tid][1] + s_red[tid][2] + s_red[tid][3];
        float s2 = s_red2[tid][0] + s_red2[tid][1] + s_red2[tid][2] + s_red2[tid][3];
        float mu = s * (1.f / Hh);
        float var = s2 * (1.f / Hh) - mu * mu;
        s_stats[tid][0] = mu;
        s_stats[tid][1] = rsqrtf(var + 1e-5f);
    }
    __syncthreads();
    #pragma unroll
    for (int n = 0; n < 4; n++) {
        int col = wc * 64 + n * 16 + l15;
        gam[n] = gupd[col]; bet[n] = beupd[col];
    }
    #pragma unroll
    for (int m = 0; m < 2; m++)
        #pragma unroll
        for (int j = 0; j < 4; j++) {
            int r = wr * 32 + m * 16 + lg * 4 + j;
            float mu = s_stats[r][0], rs = s_stats[r][1];
            float* dst = out + (size_t)(n0 + r) * Hh + wc * 64 + l15;
            #pragma unroll
            for (int n = 0; n < 4; n++) {
                float val = (acc[m][n][j] - mu) * rs * gam[n] + bet[n];
                dst[n * 16] = val;
            }
        }
}

extern "C" void kernel_launch(void* const* d_in, const int* in_sizes, int n_in,
                              void* d_out, int out_size, void* d_ws, size_t ws_size,
                              hipStream_t stream) {
    const float* nf    = (const float*)d_in[0];
    const int* members = (const int*)d_in[1];
    const int* types   = (const int*)d_in[2];
    const void* maskp  = d_in[3];
    const float* ett   = (const float*)d_in[4];
    const float* Wenc  = (const float*)d_in[5];
    const float* benc  = (const float*)d_in[6];
    const float* genc  = (const float*)d_in[7];
    const float* beenc = (const float*)d_in[8];
    const float* Wupd  = (const float*)d_in[9];
    const float* bupd  = (const float*)d_in[10];
    const float* gupd  = (const float*)d_in[11];
    const float* beupd = (const float*)d_in[12];
    float* out = (float*)d_out;

    // workspace layout
    int* ip    = (int*)d_ws;
    int* flag  = ip;                      // 64 ints
    int* deg   = ip + 64;                 // BN
    int* offs  = deg + BN;                // BN+16
    int* cur   = offs + BN + 16;          // BN
    int* iscan = cur + BN;                // BN
    int* bsums = iscan + BN;              // 64
    int* list  = bsums + 64;              // BE*Aa + 16
    char* p    = (char*)(list + BE * Aa + 16);
    u16* efb   = (u16*)p;   p += (size_t)(BE + 1) * Hh * 2;       // 20.5 MB (+zero row)
    u16* We1P  = (u16*)p;   p += (size_t)16 * KTE * 64 * 8 * 2;   // 131 KB
    u16* WupdP = (u16*)p;   p += (size_t)16 * KTU * 64 * 8 * 2;   // 262 KB
    float* tb  = (float*)p; p += (size_t)NTy * Hh * 4;            // 16 KB
    u16* nfb   = (u16*)p;   p += (size_t)BN * Hh * 2;             // 20.5 MB (optional)
    const bool use_nfbf = ((size_t)(p - (char*)d_ws) <= ws_size);

    // zero flag+deg, and the dummy efb row (graph-legal memsets)
    hipMemsetAsync(ip, 0, (size_t)(64 + BN) * 4, stream);
    hipMemsetAsync(efb + (size_t)BE * Hh, 0, (size_t)Hh * 2, stream);
    hipLaunchKernelGGL(k_detect, dim3(256), dim3(256), 0, stream,
                       (const unsigned int*)maskp, BE * Aa / 4, flag);
    hipLaunchKernelGGL(k_prep, dim3(NPREP), dim3(256), 0, stream,
                       (const float4*)nf, (ushort4*)nfb, (int)use_nfbf,
                       Wenc, We1P, Wupd, WupdP, ett, benc, tb,
                       members, maskp, flag, deg);
    hipLaunchKernelGGL(k_scan_blk, dim3(NSB), dim3(SCB), 0, stream,
                       deg, iscan, bsums);
    hipLaunchKernelGGL(k_scan_add, dim3((BN + 255) / 256), dim3(256), 0, stream,
                       iscan, deg, bsums, offs, cur);
    hipLaunchKernelGGL(k_fill, dim3(640), dim3(256), 0, stream,
                       members, maskp, flag, cur, list);
    if (use_nfbf) {
        hipLaunchKernelGGL((k_gemm_edge<true>), dim3(BE / 64), dim3(512), 0, stream,
                           nf, nfb, members, types, maskp, flag,
                           (const bf16x8*)We1P, tb, genc, beenc, (uint4*)efb);
        hipLaunchKernelGGL((k_gemm_node<true>), dim3(BN / 64), dim3(512), 0, stream,
                           nf, nfb, efb, offs, list, (const bf16x8*)WupdP,
                           bupd, gupd, beupd, out);
    } else {
        hipLaunchKernelGGL((k_gemm_edge<false>), dim3(BE / 64), dim3(512), 0, stream,
                           nf, nfb, members, types, maskp, flag,
                           (const bf16x8*)We1P, tb, genc, beenc, (uint4*)efb);
        hipLaunchKernelGGL((k_gemm_node<false>), dim3(BN / 64), dim3(512), 0, stream,
                           nf, nfb, efb, offs, list, (const bf16x8*)WupdP,
                           bupd, gupd, beupd, out);
    }
}